// Round 7
// baseline (302.831 us; speedup 1.0000x reference)
//
#include <hip/hip_runtime.h>
#include <hip/hip_bf16.h>
#include <math.h>

#define EMBED 768
#define NH 12
#define HD 64
#define SEQ 1024
#define BATCH 8
#define NROWS (BATCH * SEQ) /* 8192 */
#define LOG2E 1.44269504088896340736f

typedef __attribute__((ext_vector_type(4))) float f32x4;
typedef __attribute__((ext_vector_type(8))) short short8;
typedef __attribute__((ext_vector_type(8))) _Float16 half8;
typedef unsigned short u16;

__device__ __forceinline__ u16 f2bf(float x) {
    union { float f; unsigned u; } v; v.f = x;
    unsigned r = v.u + 0x7fff + ((v.u >> 16) & 1);   // RNE
    return (u16)(r >> 16);
}
__device__ __forceinline__ void split2h(float x, u16& hi, u16& lo) {
    _Float16 h = (_Float16)x;
    _Float16 l = (_Float16)(x - (float)h);
    union { _Float16 f; u16 u; } a, b;
    a.f = h; b.f = l;
    hi = a.u; lo = b.u;
}
__device__ __forceinline__ u16 f2h(float x) {
    union { _Float16 f; u16 u; } a; a.f = (_Float16)x; return a.u;
}
__device__ __forceinline__ unsigned pkbf(float a, float b) {
    union { __hip_bfloat162 v; unsigned u; } cv;
    cv.v = __float22bfloat162_rn(make_float2(a, b));
    return cv.u;
}
__device__ __forceinline__ void gll16(const void* g, void* l) {
    __builtin_amdgcn_global_load_lds(
        (const __attribute__((address_space(1))) unsigned int*)g,
        (__attribute__((address_space(3))) unsigned int*)l,
        16, 0, 0);
}
// waitcnt(all my vmem done) + workgroup barrier + compiler fence.
// Raw s_barrier does NOT auto-drain vmcnt (unlike __syncthreads), enabling
// the single-barrier double-buffered K-loop (AITER-style).
__device__ __forceinline__ void pipe_barrier() {
    asm volatile("s_waitcnt vmcnt(0)" ::: "memory");
    __builtin_amdgcn_s_barrier();
    asm volatile("" ::: "memory");
}

// ---------------------------------------------------------------------------
// Kernel 1: rel-pos bias table (pre-scaled by log2 e)
// ---------------------------------------------------------------------------
__global__ void bias_table_kernel(const float* __restrict__ rel_embed,
                                  float* __restrict__ bt)
{
    int idx = blockIdx.x * 256 + threadIdx.x;
    const int total = NH * 2047;
    if (idx >= total) return;
    int h    = idx / 2047;
    int dpos = idx - h * 2047;
    int rp   = dpos - 1023;
    int bucket = (rp > 0) ? 16 : 0;
    int arp = rp < 0 ? -rp : rp;
    if (arp < 8) {
        bucket += arp;
    } else {
        double v = log((double)arp / 8.0) / log(16.0) * 8.0;
        int l = 8 + (int)v;
        if (l > 15) l = 15;
        bucket += l;
    }
    bt[idx] = rel_embed[bucket * NH + h] * LOG2E;
}

// ---------------------------------------------------------------------------
// Kernel 2: gate[b,h,s]
// ---------------------------------------------------------------------------
__global__ void gate_kernel(const float* __restrict__ query,
                            const float* __restrict__ gru_W,
                            const float* __restrict__ gru_b,
                            const float* __restrict__ gru_c,
                            float* __restrict__ gate)
{
    int idx = blockIdx.x * 256 + threadIdx.x;
    if (idx >= BATCH * NH * SEQ) return;
    int s  = idx & (SEQ - 1);
    int bh = idx >> 10;
    int h  = bh % NH;
    int b  = bh / NH;

    const float* x = query + ((size_t)(b * SEQ + s) * EMBED + h * HD);
    float z[8] = {0.f, 0.f, 0.f, 0.f, 0.f, 0.f, 0.f, 0.f};
    for (int d = 0; d < HD; ++d) {
        float xv = x[d];
        const float* wrow = gru_W + d * 8;
        #pragma unroll
        for (int c = 0; c < 8; ++c) z[c] += xv * wrow[c];
    }
    float s0 = (z[0] + gru_b[0]) + (z[1] + gru_b[1]) + (z[2] + gru_b[2]) + (z[3] + gru_b[3]);
    float s1 = (z[4] + gru_b[4]) + (z[5] + gru_b[5]) + (z[6] + gru_b[6]) + (z[7] + gru_b[7]);
    float g0 = 1.f / (1.f + expf(-s0));
    float g1 = 1.f / (1.f + expf(-s1));
    gate[idx] = g0 * (g1 * gru_c[h] - 1.f) + 2.f;
}

// ---------------------------------------------------------------------------
// Kernel 3a: elementwise hi/lo f16 split of A
// ---------------------------------------------------------------------------
__global__ __launch_bounds__(256)
void convertA_h(const float* __restrict__ A, u16* __restrict__ Ah,
                u16* __restrict__ Al)
{
    int idx = (blockIdx.x * 256 + threadIdx.x) * 4;
    float4 v = *(const float4*)(A + idx);
    ushort4 h, l;
    split2h(v.x, h.x, l.x); split2h(v.y, h.y, l.y);
    split2h(v.z, h.z, l.z); split2h(v.w, h.w, l.w);
    *(ushort4*)(Ah + idx) = h;
    *(ushort4*)(Al + idx) = l;
}

// ---------------------------------------------------------------------------
// Kernel 3b: all four W [K][N] f32 -> transposed f16 [N][K], one dispatch
// ---------------------------------------------------------------------------
__global__ __launch_bounds__(256)
void convertWT4(const float* __restrict__ W0, const float* __restrict__ W1,
                const float* __restrict__ W2, const float* __restrict__ W3,
                u16* __restrict__ T0, u16* __restrict__ T1,
                u16* __restrict__ T2, u16* __restrict__ T3)
{
    __shared__ float tile[32][33];
    const float* W = (blockIdx.z == 0) ? W0 : (blockIdx.z == 1) ? W1
                   : (blockIdx.z == 2) ? W2 : W3;
    u16* WT        = (blockIdx.z == 0) ? T0 : (blockIdx.z == 1) ? T1
                   : (blockIdx.z == 2) ? T2 : T3;
    int t  = threadIdx.x;
    int k0 = blockIdx.y * 32, n0 = blockIdx.x * 32;
    int r = t >> 3, c = (t & 7) * 4;
    float4 v = *(const float4*)&W[(size_t)(k0 + r) * EMBED + n0 + c];
    tile[r][c] = v.x; tile[r][c + 1] = v.y; tile[r][c + 2] = v.z; tile[r][c + 3] = v.w;
    __syncthreads();
    int n = t >> 3, ks = (t & 7) * 4;
    ushort4 h;
    h.x = f2h(tile[ks    ][n]);
    h.y = f2h(tile[ks + 1][n]);
    h.z = f2h(tile[ks + 2][n]);
    h.w = f2h(tile[ks + 3][n]);
    *(ushort4*)&WT[(size_t)(n0 + n) * EMBED + k0 + ks] = h;
}

// ---------------------------------------------------------------------------
// Kernel 4: FUSED Q/K/V 2-term f16 GEMM, single-barrier double-buffered.
// Tile 32(M)x128(N), BK=32, grid (6,256). B (3 matrices) double-buffered in
// LDS via GLL (48 KB -> 3 blocks/CU); A frags loaded DIRECTLY to registers
// (per-lane natural layout), register-double-buffered. One s_barrier/step;
// next tile's staging overlaps current tile's compute.
// ---------------------------------------------------------------------------
__global__ __launch_bounds__(256, 3)
void gemm_qkv_p(const u16* __restrict__ Ah, const u16* __restrict__ Al,
                const u16* __restrict__ WqT, const u16* __restrict__ WkT,
                const u16* __restrict__ WvT,
                const float* __restrict__ bq, const float* __restrict__ bk,
                const float* __restrict__ bv,
                u16* __restrict__ Qb, u16* __restrict__ Kb, u16* __restrict__ VT,
                float qscale)
{
    __shared__ u16 Bs[2][3][128 * 32];   // 49152 B

    const int t    = threadIdx.x;
    const int lane = t & 63;
    const int wid  = t >> 6;
    const int L    = lane & 15;
    const int quad = lane >> 4;
    const int row0 = blockIdx.y * 32;
    const int col0 = blockIdx.x * 128;
    const int wm   = (wid >> 1) * 16;
    const int wn   = (wid & 1) * 64;

    f32x4 accQ[4], accK[4], accV[4];
    #pragma unroll
    for (int nt = 0; nt < 4; ++nt) {
        accQ[nt] = (f32x4){0.f, 0.f, 0.f, 0.f};
        accK[nt] = (f32x4){0.f, 0.f, 0.f, 0.f};
        accV[nt] = (f32x4){0.f, 0.f, 0.f, 0.f};
    }

    // B staging source mapping (chunk swizzle c^(r&3))
    const int rB = t >> 2;
    const int cB = (t & 3) ^ (rB & 3);
    const size_t bo0 = (size_t)(col0 + rB) * EMBED + 8 * cB;
    const size_t bo1 = (size_t)(col0 + 64 + rB) * EMBED + 8 * cB;

    // A direct per-lane pointers
    const u16* ApH = Ah + (size_t)(row0 + wm + L) * EMBED + quad * 8;
    const u16* ApL = Al + (size_t)(row0 + wm + L) * EMBED + quad * 8;

    const int swz = 8 * (quad ^ (L & 3));

    // prologue: stage tile 0, load A regs for tile 0
    {
        char* base = (char*)Bs + wid * 1024;
        gll16(WqT + bo0, base);             gll16(WqT + bo1, base + 4096);
        gll16(WkT + bo0, base + 8192);      gll16(WkT + bo1, base + 12288);
        gll16(WvT + bo0, base + 16384);     gll16(WvT + bo1, base + 20480);
    }
    half8 ah = *(const half8*)ApH;
    half8 al = *(const half8*)ApL;

    int cur = 0;
    for (int k0 = 0; k0 < EMBED; k0 += 32, cur ^= 1) {
        pipe_barrier();   // my vmem done + all waves' staging of buf[cur] done

        half8 ahn, aln;
        if (k0 + 32 < EMBED) {   // stage next tile into other buffer
            char* base = (char*)Bs + (cur ^ 1) * 24576 + wid * 1024;
            gll16(WqT + bo0 + k0 + 32, base);         gll16(WqT + bo1 + k0 + 32, base + 4096);
            gll16(WkT + bo0 + k0 + 32, base + 8192);  gll16(WkT + bo1 + k0 + 32, base + 12288);
            gll16(WvT + bo0 + k0 + 32, base + 16384); gll16(WvT + bo1 + k0 + 32, base + 20480);
            ahn = *(const half8*)(ApH + k0 + 32);
            aln = *(const half8*)(ApL + k0 + 32);
        }

        const u16* Bq = &Bs[cur][0][0];
        const u16* Bk = &Bs[cur][1][0];
        const u16* Bv = &Bs[cur][2][0];
        #pragma unroll
        for (int nt = 0; nt < 4; ++nt) {
            const int boff = (wn + nt * 16 + L) * 32 + swz;
            half8 b0 = *(const half8*)&Bq[boff];
            accQ[nt] = __builtin_amdgcn_mfma_f32_16x16x32_f16(ah, b0, accQ[nt], 0, 0, 0);
            accQ[nt] = __builtin_amdgcn_mfma_f32_16x16x32_f16(al, b0, accQ[nt], 0, 0, 0);
            half8 b1 = *(const half8*)&Bk[boff];
            accK[nt] = __builtin_amdgcn_mfma_f32_16x16x32_f16(ah, b1, accK[nt], 0, 0, 0);
            accK[nt] = __builtin_amdgcn_mfma_f32_16x16x32_f16(al, b1, accK[nt], 0, 0, 0);
            half8 b2 = *(const half8*)&Bv[boff];
            accV[nt] = __builtin_amdgcn_mfma_f32_16x16x32_f16(ah, b2, accV[nt], 0, 0, 0);
            accV[nt] = __builtin_amdgcn_mfma_f32_16x16x32_f16(al, b2, accV[nt], 0, 0, 0);
        }
        ah = ahn; al = aln;
    }

    float bq4[4], bk4[4], bv4[4];
    #pragma unroll
    for (int nt = 0; nt < 4; ++nt) {
        int n = col0 + wn + nt * 16 + L;
        bq4[nt] = bq[n]; bk4[nt] = bk[n]; bv4[nt] = bv[n];
    }

    const int rowa = row0 + wm + quad * 4;
    #pragma unroll
    for (int r = 0; r < 4; ++r) {
        size_t base = (size_t)(rowa + r) * EMBED + col0 + wn + L;
        #pragma unroll
        for (int nt = 0; nt < 4; ++nt) {
            Qb[base + nt * 16] = f2bf((accQ[nt][r] + bq4[nt]) * qscale);
            Kb[base + nt * 16] = f2bf(accK[nt][r] + bk4[nt]);
        }
    }
    {   // V transposed bf16: VT[((b*NH+h)*HD+d)*SEQ + s]
        int b_  = rowa >> 10;
        int s0_ = rowa & 1023;
        #pragma unroll
        for (int nt = 0; nt < 4; ++nt) {
            int n = col0 + wn + nt * 16 + L;
            int hh = n >> 6, dd = n & 63;
            ushort4 pk;
            pk.x = f2bf(accV[nt][0] + bv4[nt]);
            pk.y = f2bf(accV[nt][1] + bv4[nt]);
            pk.z = f2bf(accV[nt][2] + bv4[nt]);
            pk.w = f2bf(accV[nt][3] + bv4[nt]);
            *(ushort4*)&VT[((size_t)(b_ * NH + hh) * HD + dd) * SEQ + s0_] = pk;
        }
    }
}

// ---------------------------------------------------------------------------
// Kernel 5: output GEMM, 2-term f16, tile 64x128, BK=32, grid (6,128),
// same single-barrier double-buffered structure. B in LDS (16 KB dbuf),
// A (hi/lo) direct to registers.
// ---------------------------------------------------------------------------
__global__ __launch_bounds__(256, 3)
void gemm_out_p(const u16* __restrict__ Ah, const u16* __restrict__ Al,
                const u16* __restrict__ BT, const float* __restrict__ bias,
                float* __restrict__ C)
{
    __shared__ u16 Bs[2][128 * 32];   // 16384 B

    const int t    = threadIdx.x;
    const int lane = t & 63;
    const int wid  = t >> 6;
    const int L    = lane & 15;
    const int quad = lane >> 4;
    const int row0 = blockIdx.y * 64;
    const int col0 = blockIdx.x * 128;
    const int wm   = (wid >> 1) * 32;
    const int wn   = (wid & 1) * 64;

    f32x4 acc[2][4];
    #pragma unroll
    for (int mt = 0; mt < 2; ++mt)
        #pragma unroll
        for (int nt = 0; nt < 4; ++nt) acc[mt][nt] = (f32x4){0.f, 0.f, 0.f, 0.f};

    const int rB = t >> 2;
    const int cB = (t & 3) ^ (rB & 3);
    const size_t bo0 = (size_t)(col0 + rB) * EMBED + 8 * cB;
    const size_t bo1 = (size_t)(col0 + 64 + rB) * EMBED + 8 * cB;

    const u16* ApH[2]; const u16* ApL[2];
    #pragma unroll
    for (int mt = 0; mt < 2; ++mt) {
        ApH[mt] = Ah + (size_t)(row0 + wm + mt * 16 + L) * EMBED + quad * 8;
        ApL[mt] = Al + (size_t)(row0 + wm + mt * 16 + L) * EMBED + quad * 8;
    }

    const int swz = 8 * (quad ^ (L & 3));

    {   // prologue
        char* base = (char*)Bs + wid * 1024;
        gll16(BT + bo0, base);
        gll16(BT + bo1, base + 4096);
    }
    half8 ah[2], al[2];
    #pragma unroll
    for (int mt = 0; mt < 2; ++mt) {
        ah[mt] = *(const half8*)ApH[mt];
        al[mt] = *(const half8*)ApL[mt];
    }

    int cur = 0;
    for (int k0 = 0; k0 < EMBED; k0 += 32, cur ^= 1) {
        pipe_barrier();

        half8 ahn[2], aln[2];
        if (k0 + 32 < EMBED) {
            char* base = (char*)Bs + (cur ^ 1) * 8192 + wid * 1024;
            gll16(BT + bo0 + k0 + 32, base);
            gll16(BT + bo1 + k0 + 32, base + 4096);
            #pragma unroll
            for (int mt = 0; mt < 2; ++mt) {
                ahn[mt] = *(const half8*)(ApH[mt] + k0 + 32);
                aln[mt] = *(const half8*)(ApL[mt] + k0 + 32);
            }
        }

        const u16* B = &Bs[cur][0];
        #pragma unroll
        for (int nt = 0; nt < 4; ++nt) {
            half8 b = *(const half8*)&B[(wn + nt * 16 + L) * 32 + swz];
            #pragma unroll
            for (int mt = 0; mt < 2; ++mt) {
                acc[mt][nt] = __builtin_amdgcn_mfma_f32_16x16x32_f16(ah[mt], b, acc[mt][nt], 0, 0, 0);
                acc[mt][nt] = __builtin_amdgcn_mfma_f32_16x16x32_f16(al[mt], b, acc[mt][nt], 0, 0, 0);
            }
        }
        #pragma unroll
        for (int mt = 0; mt < 2; ++mt) { ah[mt] = ahn[mt]; al[mt] = aln[mt]; }
    }

    float b4[4];
    #pragma unroll
    for (int nt = 0; nt < 4; ++nt) b4[nt] = bias[col0 + wn + nt * 16 + L];
    #pragma unroll
    for (int mt = 0; mt < 2; ++mt)
        #pragma unroll
        for (int r = 0; r < 4; ++r) {
            size_t base = (size_t)(row0 + wm + mt * 16 + quad * 4 + r) * EMBED + col0 + wn + L;
            #pragma unroll
            for (int nt = 0; nt < 4; ++nt)
                C[base + nt * 16] = acc[mt][nt][r] + b4[nt];
        }
}

// ---------------------------------------------------------------------------
// Kernel 6: MFMA flash attention (S^T/O^T, max-free exp2) — unchanged R6.
// ---------------------------------------------------------------------------
__global__ __launch_bounds__(256)
void attn_mfma3(const u16* __restrict__ Qg, const u16* __restrict__ Kg,
                const u16* __restrict__ VTg, const float* __restrict__ gate,
                const float* __restrict__ bias_tab,
                u16* __restrict__ Oh, u16* __restrict__ Ol)
{
    __shared__ float2   btP[2047];         // 16376 B
    __shared__ u16      Klds[64 * 64];     //  8192 B  [k][d], chunk^(k&7)
    __shared__ u16      Vlds[64 * 64];     //  8192 B  [d][k], chunk^(d&7)
    __shared__ unsigned PB[4][32 * 20];    // 10240 B  per-wave [q][kp]

    const int t    = threadIdx.x;
    const int lane = t & 63;
    const int wid  = t >> 6;
    const int L    = lane & 15;
    const int quad = lane >> 4;

    const int bh = blockIdx.y;
    const int b  = bh / NH;
    const int h  = bh % NH;
    const int qw = blockIdx.x * 128 + wid * 32;

    for (int i = t; i < 2047; i += 256) {
        float a  = bias_tab[h * 2047 + i];
        float nb = (i < 2046) ? bias_tab[h * 2047 + i + 1] : 0.f;
        btP[i] = make_float2(a, nb);
    }

    short8 qf[2][2];
    int   qabs[2];
    float g2[2];
    #pragma unroll
    for (int qt = 0; qt < 2; ++qt) {
        qabs[qt] = qw + qt * 16 + L;
        g2[qt]   = gate[(size_t)bh * SEQ + qabs[qt]];
        const u16* qp = Qg + ((size_t)(b * SEQ + qabs[qt]) * EMBED + h * HD + quad * 8);
        qf[qt][0] = *(const short8*)qp;
        qf[qt][1] = *(const short8*)(qp + 32);
    }

    float lac[2] = {0.f, 0.f};
    f32x4 o[4][2];
    #pragma unroll
    for (int dt = 0; dt < 4; ++dt)
        #pragma unroll
        for (int qt = 0; qt < 2; ++qt) o[dt][qt] = (f32x4){0.f, 0.f, 0.f, 0.f};

    const int k_a = t >> 3, c_a = (t & 7) ^ (k_a & 7);
    const u16* gK0 = Kg + ((size_t)(b * SEQ + k_a) * EMBED + h * HD + 8 * c_a);
    const u16* gK1 = Kg + ((size_t)(b * SEQ + 32 + k_a) * EMBED + h * HD + 8 * c_a);
    char* lK0 = (char*)Klds + wid * 1024;
    char* lK1 = (char*)Klds + 4096 + wid * 1024;

    const int d_a = t >> 3, cv_a = (t & 7) ^ (d_a & 7);
    const u16* gV0 = VTg + ((size_t)(bh * HD + d_a) * SEQ + 8 * cv_a);
    const u16* gV1 = VTg + ((size_t)(bh * HD + 32 + d_a) * SEQ + 8 * cv_a);
    char* lV0 = (char*)Vlds + wid * 1024;
    char* lV1 = (char*)Vlds + 4096 + wid * 1024;

    unsigned* PBw = PB[wid];

    for (int k0 = 0; k0 < SEQ; k0 += 64) {
        __syncthreads();
        gll16(gK0 + (size_t)k0 * EMBED, lK0);
        gll16(gK1 + (size_t)k0 * EMBED, lK1);
        gll16(gV0 + k0, lV0);
        gll16(gV1 + k0, lV1);
        __syncthreads();

        f32x4 st[4][2];
        #pragma unroll
        for (int kt = 0; kt < 4; ++kt)
            #pragma unroll
            for (int qt = 0; qt < 2; ++qt) st[kt][qt] = (f32x4){0.f, 0.f, 0.f, 0.f};
        #pragma unroll
        for (int c = 0; c < 2; ++c) {
            #pragma unroll
            for (int kt = 0; kt < 4; ++kt) {
                int krow = kt * 16 + L;
                short8 kf = *(const short8*)&Klds[krow * 64 + 8 * ((c * 4 + quad) ^ (krow & 7))];
                st[kt][0] = __builtin_amdgcn_mfma_f32_16x16x32_bf16(kf, qf[0][c], st[kt][0], 0, 0, 0);
                st[kt][1] = __builtin_amdgcn_mfma_f32_16x16x32_bf16(kf, qf[1][c], st[kt][1], 0, 0, 0);
            }
        }

        #pragma unroll
        for (int c = 0; c < 2; ++c) {
            #pragma unroll
            for (int kt2 = 0; kt2 < 2; ++kt2) {
                int kt = c * 2 + kt2;
                #pragma unroll
                for (int qt = 0; qt < 2; ++qt) {
                    int bidx = k0 + kt * 16 + quad * 4 - qabs[qt] + 1023;
                    float2 u = btP[bidx];
                    float2 v = btP[bidx + 2];
                    float p0 = __builtin_amdgcn_exp2f(st[kt][qt][0] + g2[qt] * u.x);
                    float p1 = __builtin_amdgcn_exp2f(st[kt][qt][1] + g2[qt] * u.y);
                    float p2 = __builtin_amdgcn_exp2f(st[kt][qt][2] + g2[qt] * v.x);
                    float p3 = __builtin_amdgcn_exp2f(st[kt][qt][3] + g2[qt] * v.y);
                    lac[qt] += (p0 + p1) + (p2 + p3);
                    uint2 w;
                    w.x = pkbf(p0, p1);
                    w.y = pkbf(p2, p3);
                    *(uint2*)&PBw[(qt * 16 + L) * 20 + kt2 * 8 + quad * 2] = w;
                }
            }
            short8 pb[2];
            #pragma unroll
            for (int qt = 0; qt < 2; ++qt) {
                union { uint4 u4; short8 v; } w;
                w.u4 = *(const uint4*)&PBw[(qt * 16 + L) * 20 + quad * 4];
                pb[qt] = w.v;
            }
            #pragma unroll
            for (int dt = 0; dt < 4; ++dt) {
                int drow = dt * 16 + L;
                short8 vf = *(const short8*)&Vlds[drow * 64 + 8 * ((c * 4 + quad) ^ (drow & 7))];
                o[dt][0] = __builtin_amdgcn_mfma_f32_16x16x32_bf16(vf, pb[0], o[dt][0], 0, 0, 0);
                o[dt][1] = __builtin_amdgcn_mfma_f32_16x16x32_bf16(vf, pb[1], o[dt][1], 0, 0, 0);
            }
        }
    }

    #pragma unroll
    for (int qt = 0; qt < 2; ++qt) {
        lac[qt] += __shfl_xor(lac[qt], 16);
        lac[qt] += __shfl_xor(lac[qt], 32);
    }
    #pragma unroll
    for (int qt = 0; qt < 2; ++qt) {
        float inv = 1.f / lac[qt];
        #pragma unroll
        for (int dt = 0; dt < 4; ++dt) {
            ushort4 h4, l4;
            split2h(o[dt][qt][0] * inv, h4.x, l4.x);
            split2h(o[dt][qt][1] * inv, h4.y, l4.y);
            split2h(o[dt][qt][2] * inv, h4.z, l4.z);
            split2h(o[dt][qt][3] * inv, h4.w, l4.w);
            size_t base = (size_t)(b * SEQ + qabs[qt]) * EMBED + h * HD + dt * 16 + quad * 4;
            *(ushort4*)&Oh[base] = h4;
            *(ushort4*)&Ol[base] = l4;
        }
    }
}

// ---------------------------------------------------------------------------
extern "C" void kernel_launch(void* const* d_in, const int* in_sizes, int n_in,
                              void* d_out, int out_size, void* d_ws, size_t ws_size,
                              hipStream_t stream)
{
    (void)in_sizes; (void)n_in; (void)out_size; (void)ws_size;
    const float* query = (const float*)d_in[0];
    const float* Wq    = (const float*)d_in[1];
    const float* bq    = (const float*)d_in[2];
    const float* Wk    = (const float*)d_in[3];
    const float* bk    = (const float*)d_in[4];
    const float* Wv    = (const float*)d_in[5];
    const float* bv    = (const float*)d_in[6];
    const float* Wo    = (const float*)d_in[7];
    const float* bo    = (const float*)d_in[8];
    const float* rel   = (const float*)d_in[9];
    const float* gruW  = (const float*)d_in[10];
    const float* gruB  = (const float*)d_in[11];
    const float* gruC  = (const float*)d_in[12];
    float* out = (float*)d_out;

    const size_t NE = (size_t)NROWS * EMBED;   // 6,291,456
    const size_t WN = (size_t)EMBED * EMBED;   //   589,824
    u16* ws   = (u16*)d_ws;
    u16* Ah   = ws;                 // f16 hi of query
    u16* Al   = Ah + NE;            // f16 lo
    u16* WqT  = Al + NE;            // f16 [N][K]
    u16* WkT  = WqT + WN;
    u16* WvT  = WkT + WN;
    u16* WoT  = WvT + WN;
    u16* Qb   = WoT + WN;           // bf16
    u16* Kb   = Qb + NE;
    u16* VT   = Kb + NE;            // bf16 transposed [b,h,d,s]
    u16* Ohb  = VT + NE;            // f16 hi of attn out
    u16* Olb  = Ohb + NE;           // f16 lo
    float* gate = (float*)(Olb + NE);
    float* bt   = gate + (size_t)BATCH * NH * SEQ;

    bias_table_kernel<<<(NH * 2047 + 255) / 256, 256, 0, stream>>>(rel, bt);
    gate_kernel<<<(BATCH * NH * SEQ + 255) / 256, 256, 0, stream>>>(query, gruW, gruB, gruC, gate);

    convertA_h<<<NE / 1024, 256, 0, stream>>>(query, Ah, Al);
    convertWT4<<<dim3(EMBED / 32, EMBED / 32, 4), 256, 0, stream>>>(
        Wq, Wk, Wv, Wo, WqT, WkT, WvT, WoT);

    dim3 gq(EMBED / 128, NROWS / 32);  // (6, 256)
    gemm_qkv_p<<<gq, 256, 0, stream>>>(Ah, Al, WqT, WkT, WvT, bq, bk, bv,
                                       Qb, Kb, VT, 0.125f * LOG2E);

    attn_mfma3<<<dim3(SEQ / 128, BATCH * NH), 256, 0, stream>>>(Qb, Kb, VT, gate, bt, Ohb, Olb);

    dim3 go(EMBED / 128, NROWS / 64);  // (6, 128)
    gemm_out_p<<<go, 256, 0, stream>>>(Ohb, Olb, WoT, bo, out);
}

// Round 8
// 245.265 us; speedup vs baseline: 1.2347x; 1.2347x over previous
//
#include <hip/hip_runtime.h>
#include <hip/hip_bf16.h>
#include <math.h>

#define EMBED 768
#define NH 12
#define HD 64
#define SEQ 1024
#define BATCH 8
#define NROWS (BATCH * SEQ) /* 8192 */
#define LOG2E 1.44269504088896340736f

typedef __attribute__((ext_vector_type(4))) float f32x4;
typedef __attribute__((ext_vector_type(8))) short short8;
typedef __attribute__((ext_vector_type(8))) _Float16 half8;
typedef unsigned short u16;

__device__ __forceinline__ u16 f2bf(float x) {
    union { float f; unsigned u; } v; v.f = x;
    unsigned r = v.u + 0x7fff + ((v.u >> 16) & 1);   // RNE
    return (u16)(r >> 16);
}
__device__ __forceinline__ u16 f2h(float x) {
    union { _Float16 f; u16 u; } a; a.f = (_Float16)x; return a.u;
}
__device__ __forceinline__ unsigned pkbf(float a, float b) {
    union { __hip_bfloat162 v; unsigned u; } cv;
    cv.v = __float22bfloat162_rn(make_float2(a, b));
    return cv.u;
}
__device__ __forceinline__ void gll16(const void* g, void* l) {
    __builtin_amdgcn_global_load_lds(
        (const __attribute__((address_space(1))) unsigned int*)g,
        (__attribute__((address_space(3))) unsigned int*)l,
        16, 0, 0);
}
// wait own vmem + workgroup barrier (raw s_barrier does not drain vmcnt)
__device__ __forceinline__ void pipe_barrier() {
    asm volatile("s_waitcnt vmcnt(0)" ::: "memory");
    __builtin_amdgcn_s_barrier();
    asm volatile("" ::: "memory");
}

// ---------------------------------------------------------------------------
// Kernel 1: rel-pos bias table (pre-scaled by log2 e)
// ---------------------------------------------------------------------------
__global__ void bias_table_kernel(const float* __restrict__ rel_embed,
                                  float* __restrict__ bt)
{
    int idx = blockIdx.x * 256 + threadIdx.x;
    const int total = NH * 2047;
    if (idx >= total) return;
    int h    = idx / 2047;
    int dpos = idx - h * 2047;
    int rp   = dpos - 1023;
    int bucket = (rp > 0) ? 16 : 0;
    int arp = rp < 0 ? -rp : rp;
    if (arp < 8) {
        bucket += arp;
    } else {
        double v = log((double)arp / 8.0) / log(16.0) * 8.0;
        int l = 8 + (int)v;
        if (l > 15) l = 15;
        bucket += l;
    }
    bt[idx] = rel_embed[bucket * NH + h] * LOG2E;
}

// ---------------------------------------------------------------------------
// Kernel 2: gate[b,h,s]
// ---------------------------------------------------------------------------
__global__ void gate_kernel(const float* __restrict__ query,
                            const float* __restrict__ gru_W,
                            const float* __restrict__ gru_b,
                            const float* __restrict__ gru_c,
                            float* __restrict__ gate)
{
    int idx = blockIdx.x * 256 + threadIdx.x;
    if (idx >= BATCH * NH * SEQ) return;
    int s  = idx & (SEQ - 1);
    int bh = idx >> 10;
    int h  = bh % NH;
    int b  = bh / NH;

    const float* x = query + ((size_t)(b * SEQ + s) * EMBED + h * HD);
    float z[8] = {0.f, 0.f, 0.f, 0.f, 0.f, 0.f, 0.f, 0.f};
    for (int d = 0; d < HD; ++d) {
        float xv = x[d];
        const float* wrow = gru_W + d * 8;
        #pragma unroll
        for (int c = 0; c < 8; ++c) z[c] += xv * wrow[c];
    }
    float s0 = (z[0] + gru_b[0]) + (z[1] + gru_b[1]) + (z[2] + gru_b[2]) + (z[3] + gru_b[3]);
    float s1 = (z[4] + gru_b[4]) + (z[5] + gru_b[5]) + (z[6] + gru_b[6]) + (z[7] + gru_b[7]);
    float g0 = 1.f / (1.f + expf(-s0));
    float g1 = 1.f / (1.f + expf(-s1));
    gate[idx] = g0 * (g1 * gru_c[h] - 1.f) + 2.f;
}

// ---------------------------------------------------------------------------
// Kernel 3a: A f32 -> f16 (hi only; single-term GEMM)
// ---------------------------------------------------------------------------
__global__ __launch_bounds__(256)
void convertA1(const float* __restrict__ A, u16* __restrict__ Ah)
{
    int idx = (blockIdx.x * 256 + threadIdx.x) * 4;
    float4 v = *(const float4*)(A + idx);
    ushort4 h;
    h.x = f2h(v.x); h.y = f2h(v.y); h.z = f2h(v.z); h.w = f2h(v.w);
    *(ushort4*)(Ah + idx) = h;
}

// ---------------------------------------------------------------------------
// Kernel 3b: all four W [K][N] f32 -> transposed f16 [N][K], one dispatch
// ---------------------------------------------------------------------------
__global__ __launch_bounds__(256)
void convertWT4(const float* __restrict__ W0, const float* __restrict__ W1,
                const float* __restrict__ W2, const float* __restrict__ W3,
                u16* __restrict__ T0, u16* __restrict__ T1,
                u16* __restrict__ T2, u16* __restrict__ T3)
{
    __shared__ float tile[32][33];
    const float* W = (blockIdx.z == 0) ? W0 : (blockIdx.z == 1) ? W1
                   : (blockIdx.z == 2) ? W2 : W3;
    u16* WT        = (blockIdx.z == 0) ? T0 : (blockIdx.z == 1) ? T1
                   : (blockIdx.z == 2) ? T2 : T3;
    int t  = threadIdx.x;
    int k0 = blockIdx.y * 32, n0 = blockIdx.x * 32;
    int r = t >> 3, c = (t & 7) * 4;
    float4 v = *(const float4*)&W[(size_t)(k0 + r) * EMBED + n0 + c];
    tile[r][c] = v.x; tile[r][c + 1] = v.y; tile[r][c + 2] = v.z; tile[r][c + 3] = v.w;
    __syncthreads();
    int n = t >> 3, ks = (t & 7) * 4;
    ushort4 h;
    h.x = f2h(tile[ks    ][n]);
    h.y = f2h(tile[ks + 1][n]);
    h.z = f2h(tile[ks + 2][n]);
    h.w = f2h(tile[ks + 3][n]);
    *(ushort4*)&WT[(size_t)(n0 + n) * EMBED + k0 + ks] = h;
}

// ---------------------------------------------------------------------------
// Kernel 4: FUSED Q/K/V single-term f16 GEMM, single-barrier double-buffered.
// Tile 64(M)x128(N), BK=32, grid (6,128)=768 blocks = ONE round of 3/CU.
// B (3 matrices) dbuf in LDS via GLL (48 KB); A hi loaded directly to regs.
// LDS chunk swizzle c^((row>>1)&3): parity-based -> free 2-way reads.
// ---------------------------------------------------------------------------
__global__ __launch_bounds__(256, 3)
void gemm_qkv_s(const u16* __restrict__ Ah,
                const u16* __restrict__ WqT, const u16* __restrict__ WkT,
                const u16* __restrict__ WvT,
                const float* __restrict__ bq, const float* __restrict__ bk,
                const float* __restrict__ bv,
                u16* __restrict__ Qb, u16* __restrict__ Kb, u16* __restrict__ VT,
                float qscale)
{
    __shared__ u16 Bs[2][3][128 * 32];   // 49152 B

    const int t    = threadIdx.x;
    const int lane = t & 63;
    const int wid  = t >> 6;
    const int L    = lane & 15;
    const int quad = lane >> 4;
    const int row0 = blockIdx.y * 64;
    const int col0 = blockIdx.x * 128;
    const int wm   = (wid >> 1) * 32;
    const int wn   = (wid & 1) * 64;

    f32x4 accQ[2][4], accK[2][4], accV[2][4];
    #pragma unroll
    for (int mt = 0; mt < 2; ++mt)
        #pragma unroll
        for (int nt = 0; nt < 4; ++nt) {
            accQ[mt][nt] = (f32x4){0.f, 0.f, 0.f, 0.f};
            accK[mt][nt] = (f32x4){0.f, 0.f, 0.f, 0.f};
            accV[mt][nt] = (f32x4){0.f, 0.f, 0.f, 0.f};
        }

    // B staging mapping (chunk swizzle c ^ ((r>>1)&3))
    const int rB = t >> 2;
    const int cB = (t & 3) ^ ((rB >> 1) & 3);
    const size_t bo0 = (size_t)(col0 + rB) * EMBED + 8 * cB;
    const size_t bo1 = (size_t)(col0 + 64 + rB) * EMBED + 8 * cB;

    // A hi direct per-lane pointers (rows wm+mt*16+L)
    const u16* ApH[2];
    #pragma unroll
    for (int mt = 0; mt < 2; ++mt)
        ApH[mt] = Ah + (size_t)(row0 + wm + mt * 16 + L) * EMBED + quad * 8;

    const int swz = 8 * (quad ^ ((L >> 1) & 3));

    {   // prologue: stage tile 0
        char* base = (char*)Bs + wid * 1024;
        gll16(WqT + bo0, base);             gll16(WqT + bo1, base + 4096);
        gll16(WkT + bo0, base + 8192);      gll16(WkT + bo1, base + 12288);
        gll16(WvT + bo0, base + 16384);     gll16(WvT + bo1, base + 20480);
    }
    half8 ah[2];
    #pragma unroll
    for (int mt = 0; mt < 2; ++mt) ah[mt] = *(const half8*)ApH[mt];

    int cur = 0;
    for (int k0 = 0; k0 < EMBED; k0 += 32, cur ^= 1) {
        pipe_barrier();

        half8 ahn[2];
        if (k0 + 32 < EMBED) {
            char* base = (char*)Bs + (cur ^ 1) * 24576 + wid * 1024;
            gll16(WqT + bo0 + k0 + 32, base);         gll16(WqT + bo1 + k0 + 32, base + 4096);
            gll16(WkT + bo0 + k0 + 32, base + 8192);  gll16(WkT + bo1 + k0 + 32, base + 12288);
            gll16(WvT + bo0 + k0 + 32, base + 16384); gll16(WvT + bo1 + k0 + 32, base + 20480);
            #pragma unroll
            for (int mt = 0; mt < 2; ++mt) ahn[mt] = *(const half8*)(ApH[mt] + k0 + 32);
        }

        const u16* Bq = &Bs[cur][0][0];
        const u16* Bk = &Bs[cur][1][0];
        const u16* Bv = &Bs[cur][2][0];
        #pragma unroll
        for (int nt = 0; nt < 4; ++nt) {
            const int boff = (wn + nt * 16 + L) * 32 + swz;
            half8 b0 = *(const half8*)&Bq[boff];
            accQ[0][nt] = __builtin_amdgcn_mfma_f32_16x16x32_f16(ah[0], b0, accQ[0][nt], 0, 0, 0);
            accQ[1][nt] = __builtin_amdgcn_mfma_f32_16x16x32_f16(ah[1], b0, accQ[1][nt], 0, 0, 0);
            half8 b1 = *(const half8*)&Bk[boff];
            accK[0][nt] = __builtin_amdgcn_mfma_f32_16x16x32_f16(ah[0], b1, accK[0][nt], 0, 0, 0);
            accK[1][nt] = __builtin_amdgcn_mfma_f32_16x16x32_f16(ah[1], b1, accK[1][nt], 0, 0, 0);
            half8 b2 = *(const half8*)&Bv[boff];
            accV[0][nt] = __builtin_amdgcn_mfma_f32_16x16x32_f16(ah[0], b2, accV[0][nt], 0, 0, 0);
            accV[1][nt] = __builtin_amdgcn_mfma_f32_16x16x32_f16(ah[1], b2, accV[1][nt], 0, 0, 0);
        }
        #pragma unroll
        for (int mt = 0; mt < 2; ++mt) ah[mt] = ahn[mt];
    }

    float bq4[4], bk4[4], bv4[4];
    #pragma unroll
    for (int nt = 0; nt < 4; ++nt) {
        int n = col0 + wn + nt * 16 + L;
        bq4[nt] = bq[n]; bk4[nt] = bk[n]; bv4[nt] = bv[n];
    }

    #pragma unroll
    for (int mt = 0; mt < 2; ++mt) {
        const int rowa = row0 + wm + mt * 16 + quad * 4;
        #pragma unroll
        for (int r = 0; r < 4; ++r) {
            size_t base = (size_t)(rowa + r) * EMBED + col0 + wn + L;
            #pragma unroll
            for (int nt = 0; nt < 4; ++nt) {
                Qb[base + nt * 16] = f2bf((accQ[mt][nt][r] + bq4[nt]) * qscale);
                Kb[base + nt * 16] = f2bf(accK[mt][nt][r] + bk4[nt]);
            }
        }
        {   // V transposed bf16: VT[((b*NH+h)*HD+d)*SEQ + s]
            int b_  = rowa >> 10;
            int s0_ = rowa & 1023;
            #pragma unroll
            for (int nt = 0; nt < 4; ++nt) {
                int n = col0 + wn + nt * 16 + L;
                int hh = n >> 6, dd = n & 63;
                ushort4 pk;
                pk.x = f2bf(accV[mt][nt][0] + bv4[nt]);
                pk.y = f2bf(accV[mt][nt][1] + bv4[nt]);
                pk.z = f2bf(accV[mt][nt][2] + bv4[nt]);
                pk.w = f2bf(accV[mt][nt][3] + bv4[nt]);
                *(ushort4*)&VT[((size_t)(b_ * NH + hh) * HD + dd) * SEQ + s0_] = pk;
            }
        }
    }
}

// ---------------------------------------------------------------------------
// Kernel 5: output GEMM, single-term f16, tile 64x128, BK=32, grid (6,128).
// ---------------------------------------------------------------------------
__global__ __launch_bounds__(256, 3)
void gemm_out_s(const u16* __restrict__ Ah, const u16* __restrict__ BT,
                const float* __restrict__ bias, float* __restrict__ C)
{
    __shared__ u16 Bs[2][128 * 32];   // 16384 B

    const int t    = threadIdx.x;
    const int lane = t & 63;
    const int wid  = t >> 6;
    const int L    = lane & 15;
    const int quad = lane >> 4;
    const int row0 = blockIdx.y * 64;
    const int col0 = blockIdx.x * 128;
    const int wm   = (wid >> 1) * 32;
    const int wn   = (wid & 1) * 64;

    f32x4 acc[2][4];
    #pragma unroll
    for (int mt = 0; mt < 2; ++mt)
        #pragma unroll
        for (int nt = 0; nt < 4; ++nt) acc[mt][nt] = (f32x4){0.f, 0.f, 0.f, 0.f};

    const int rB = t >> 2;
    const int cB = (t & 3) ^ ((rB >> 1) & 3);
    const size_t bo0 = (size_t)(col0 + rB) * EMBED + 8 * cB;
    const size_t bo1 = (size_t)(col0 + 64 + rB) * EMBED + 8 * cB;

    const u16* ApH[2];
    #pragma unroll
    for (int mt = 0; mt < 2; ++mt)
        ApH[mt] = Ah + (size_t)(row0 + wm + mt * 16 + L) * EMBED + quad * 8;

    const int swz = 8 * (quad ^ ((L >> 1) & 3));

    {   // prologue
        char* base = (char*)Bs + wid * 1024;
        gll16(BT + bo0, base);
        gll16(BT + bo1, base + 4096);
    }
    half8 ah[2];
    #pragma unroll
    for (int mt = 0; mt < 2; ++mt) ah[mt] = *(const half8*)ApH[mt];

    int cur = 0;
    for (int k0 = 0; k0 < EMBED; k0 += 32, cur ^= 1) {
        pipe_barrier();

        half8 ahn[2];
        if (k0 + 32 < EMBED) {
            char* base = (char*)Bs + (cur ^ 1) * 8192 + wid * 1024;
            gll16(BT + bo0 + k0 + 32, base);
            gll16(BT + bo1 + k0 + 32, base + 4096);
            #pragma unroll
            for (int mt = 0; mt < 2; ++mt) ahn[mt] = *(const half8*)(ApH[mt] + k0 + 32);
        }

        const u16* B = &Bs[cur][0];
        #pragma unroll
        for (int nt = 0; nt < 4; ++nt) {
            half8 b = *(const half8*)&B[(wn + nt * 16 + L) * 32 + swz];
            #pragma unroll
            for (int mt = 0; mt < 2; ++mt)
                acc[mt][nt] = __builtin_amdgcn_mfma_f32_16x16x32_f16(ah[mt], b, acc[mt][nt], 0, 0, 0);
        }
        #pragma unroll
        for (int mt = 0; mt < 2; ++mt) ah[mt] = ahn[mt];
    }

    float b4[4];
    #pragma unroll
    for (int nt = 0; nt < 4; ++nt) b4[nt] = bias[col0 + wn + nt * 16 + L];
    #pragma unroll
    for (int mt = 0; mt < 2; ++mt)
        #pragma unroll
        for (int r = 0; r < 4; ++r) {
            size_t base = (size_t)(row0 + wm + mt * 16 + quad * 4 + r) * EMBED + col0 + wn + L;
            #pragma unroll
            for (int nt = 0; nt < 4; ++nt)
                C[base + nt * 16] = acc[mt][nt][r] + b4[nt];
        }
}

// ---------------------------------------------------------------------------
// Kernel 6: MFMA flash attention (S^T/O^T, max-free exp2).
// Output: single f16 O (single-term out-GEMM).
// ---------------------------------------------------------------------------
__global__ __launch_bounds__(256)
void attn_mfma3(const u16* __restrict__ Qg, const u16* __restrict__ Kg,
                const u16* __restrict__ VTg, const float* __restrict__ gate,
                const float* __restrict__ bias_tab,
                u16* __restrict__ Oh)
{
    __shared__ float2   btP[2047];         // 16376 B
    __shared__ u16      Klds[64 * 64];     //  8192 B  [k][d], chunk^(k&7)
    __shared__ u16      Vlds[64 * 64];     //  8192 B  [d][k], chunk^(d&7)
    __shared__ unsigned PB[4][32 * 20];    // 10240 B  per-wave [q][kp]

    const int t    = threadIdx.x;
    const int lane = t & 63;
    const int wid  = t >> 6;
    const int L    = lane & 15;
    const int quad = lane >> 4;

    const int bh = blockIdx.y;
    const int b  = bh / NH;
    const int h  = bh % NH;
    const int qw = blockIdx.x * 128 + wid * 32;

    for (int i = t; i < 2047; i += 256) {
        float a  = bias_tab[h * 2047 + i];
        float nb = (i < 2046) ? bias_tab[h * 2047 + i + 1] : 0.f;
        btP[i] = make_float2(a, nb);
    }

    short8 qf[2][2];
    int   qabs[2];
    float g2[2];
    #pragma unroll
    for (int qt = 0; qt < 2; ++qt) {
        qabs[qt] = qw + qt * 16 + L;
        g2[qt]   = gate[(size_t)bh * SEQ + qabs[qt]];
        const u16* qp = Qg + ((size_t)(b * SEQ + qabs[qt]) * EMBED + h * HD + quad * 8);
        qf[qt][0] = *(const short8*)qp;
        qf[qt][1] = *(const short8*)(qp + 32);
    }

    float lac[2] = {0.f, 0.f};
    f32x4 o[4][2];
    #pragma unroll
    for (int dt = 0; dt < 4; ++dt)
        #pragma unroll
        for (int qt = 0; qt < 2; ++qt) o[dt][qt] = (f32x4){0.f, 0.f, 0.f, 0.f};

    const int k_a = t >> 3, c_a = (t & 7) ^ (k_a & 7);
    const u16* gK0 = Kg + ((size_t)(b * SEQ + k_a) * EMBED + h * HD + 8 * c_a);
    const u16* gK1 = Kg + ((size_t)(b * SEQ + 32 + k_a) * EMBED + h * HD + 8 * c_a);
    char* lK0 = (char*)Klds + wid * 1024;
    char* lK1 = (char*)Klds + 4096 + wid * 1024;

    const int d_a = t >> 3, cv_a = (t & 7) ^ (d_a & 7);
    const u16* gV0 = VTg + ((size_t)(bh * HD + d_a) * SEQ + 8 * cv_a);
    const u16* gV1 = VTg + ((size_t)(bh * HD + 32 + d_a) * SEQ + 8 * cv_a);
    char* lV0 = (char*)Vlds + wid * 1024;
    char* lV1 = (char*)Vlds + 4096 + wid * 1024;

    unsigned* PBw = PB[wid];

    for (int k0 = 0; k0 < SEQ; k0 += 64) {
        __syncthreads();
        gll16(gK0 + (size_t)k0 * EMBED, lK0);
        gll16(gK1 + (size_t)k0 * EMBED, lK1);
        gll16(gV0 + k0, lV0);
        gll16(gV1 + k0, lV1);
        __syncthreads();

        f32x4 st[4][2];
        #pragma unroll
        for (int kt = 0; kt < 4; ++kt)
            #pragma unroll
            for (int qt = 0; qt < 2; ++qt) st[kt][qt] = (f32x4){0.f, 0.f, 0.f, 0.f};
        #pragma unroll
        for (int c = 0; c < 2; ++c) {
            #pragma unroll
            for (int kt = 0; kt < 4; ++kt) {
                int krow = kt * 16 + L;
                short8 kf = *(const short8*)&Klds[krow * 64 + 8 * ((c * 4 + quad) ^ (krow & 7))];
                st[kt][0] = __builtin_amdgcn_mfma_f32_16x16x32_bf16(kf, qf[0][c], st[kt][0], 0, 0, 0);
                st[kt][1] = __builtin_amdgcn_mfma_f32_16x16x32_bf16(kf, qf[1][c], st[kt][1], 0, 0, 0);
            }
        }

        #pragma unroll
        for (int c = 0; c < 2; ++c) {
            #pragma unroll
            for (int kt2 = 0; kt2 < 2; ++kt2) {
                int kt = c * 2 + kt2;
                #pragma unroll
                for (int qt = 0; qt < 2; ++qt) {
                    int bidx = k0 + kt * 16 + quad * 4 - qabs[qt] + 1023;
                    float2 u = btP[bidx];
                    float2 v = btP[bidx + 2];
                    float p0 = __builtin_amdgcn_exp2f(st[kt][qt][0] + g2[qt] * u.x);
                    float p1 = __builtin_amdgcn_exp2f(st[kt][qt][1] + g2[qt] * u.y);
                    float p2 = __builtin_amdgcn_exp2f(st[kt][qt][2] + g2[qt] * v.x);
                    float p3 = __builtin_amdgcn_exp2f(st[kt][qt][3] + g2[qt] * v.y);
                    lac[qt] += (p0 + p1) + (p2 + p3);
                    uint2 w;
                    w.x = pkbf(p0, p1);
                    w.y = pkbf(p2, p3);
                    *(uint2*)&PBw[(qt * 16 + L) * 20 + kt2 * 8 + quad * 2] = w;
                }
            }
            short8 pb[2];
            #pragma unroll
            for (int qt = 0; qt < 2; ++qt) {
                union { uint4 u4; short8 v; } w;
                w.u4 = *(const uint4*)&PBw[(qt * 16 + L) * 20 + quad * 4];
                pb[qt] = w.v;
            }
            #pragma unroll
            for (int dt = 0; dt < 4; ++dt) {
                int drow = dt * 16 + L;
                short8 vf = *(const short8*)&Vlds[drow * 64 + 8 * ((c * 4 + quad) ^ (drow & 7))];
                o[dt][0] = __builtin_amdgcn_mfma_f32_16x16x32_bf16(vf, pb[0], o[dt][0], 0, 0, 0);
                o[dt][1] = __builtin_amdgcn_mfma_f32_16x16x32_bf16(vf, pb[1], o[dt][1], 0, 0, 0);
            }
        }
    }

    #pragma unroll
    for (int qt = 0; qt < 2; ++qt) {
        lac[qt] += __shfl_xor(lac[qt], 16);
        lac[qt] += __shfl_xor(lac[qt], 32);
    }
    #pragma unroll
    for (int qt = 0; qt < 2; ++qt) {
        float inv = 1.f / lac[qt];
        #pragma unroll
        for (int dt = 0; dt < 4; ++dt) {
            ushort4 h4;
            h4.x = f2h(o[dt][qt][0] * inv);
            h4.y = f2h(o[dt][qt][1] * inv);
            h4.z = f2h(o[dt][qt][2] * inv);
            h4.w = f2h(o[dt][qt][3] * inv);
            size_t base = (size_t)(b * SEQ + qabs[qt]) * EMBED + h * HD + dt * 16 + quad * 4;
            *(ushort4*)&Oh[base] = h4;
        }
    }
}

// ---------------------------------------------------------------------------
extern "C" void kernel_launch(void* const* d_in, const int* in_sizes, int n_in,
                              void* d_out, int out_size, void* d_ws, size_t ws_size,
                              hipStream_t stream)
{
    (void)in_sizes; (void)n_in; (void)out_size; (void)ws_size;
    const float* query = (const float*)d_in[0];
    const float* Wq    = (const float*)d_in[1];
    const float* bq    = (const float*)d_in[2];
    const float* Wk    = (const float*)d_in[3];
    const float* bk    = (const float*)d_in[4];
    const float* Wv    = (const float*)d_in[5];
    const float* bv    = (const float*)d_in[6];
    const float* Wo    = (const float*)d_in[7];
    const float* bo    = (const float*)d_in[8];
    const float* rel   = (const float*)d_in[9];
    const float* gruW  = (const float*)d_in[10];
    const float* gruB  = (const float*)d_in[11];
    const float* gruC  = (const float*)d_in[12];
    float* out = (float*)d_out;

    const size_t NE = (size_t)NROWS * EMBED;   // 6,291,456
    const size_t WN = (size_t)EMBED * EMBED;   //   589,824
    u16* ws   = (u16*)d_ws;
    u16* Ah   = ws;                 // f16 of query
    u16* WqT  = Ah + NE;            // f16 [N][K]
    u16* WkT  = WqT + WN;
    u16* WvT  = WkT + WN;
    u16* WoT  = WvT + WN;
    u16* Qb   = WoT + WN;           // bf16
    u16* Kb   = Qb + NE;
    u16* VT   = Kb + NE;            // bf16 transposed [b,h,d,s]
    u16* Ohh  = VT + NE;            // f16 attn out
    float* gate = (float*)(Ohh + NE);
    float* bt   = gate + (size_t)BATCH * NH * SEQ;

    bias_table_kernel<<<(NH * 2047 + 255) / 256, 256, 0, stream>>>(rel, bt);
    gate_kernel<<<(BATCH * NH * SEQ + 255) / 256, 256, 0, stream>>>(query, gruW, gruB, gruC, gate);

    convertA1<<<NE / 1024, 256, 0, stream>>>(query, Ah);
    convertWT4<<<dim3(EMBED / 32, EMBED / 32, 4), 256, 0, stream>>>(
        Wq, Wk, Wv, Wo, WqT, WkT, WvT, WoT);

    dim3 gg(EMBED / 128, NROWS / 64);  // (6, 128) = 768 blocks, one round
    gemm_qkv_s<<<gg, 256, 0, stream>>>(Ah, WqT, WkT, WvT, bq, bk, bv,
                                       Qb, Kb, VT, 0.125f * LOG2E);

    attn_mfma3<<<dim3(SEQ / 128, BATCH * NH), 256, 0, stream>>>(Qb, Kb, VT, gate, bt, Ohh);

    gemm_out_s<<<gg, 256, 0, stream>>>(Ohh, WoT, bo, out);
}